// Round 13
// baseline (131.722 us; speedup 1.0000x reference)
//
#include <hip/hip_runtime.h>
#include <hip/hip_bf16.h>
#include <math.h>

#define NPTS   16384
#define NCH    8
#define MT     32    // rows per block
#define LSTR   264   // act row stride (ushort)
#define SEG    16384 // fixed bucket segment per chart
#define PSEG   2048  // points per scatter sub-segment

typedef short bf16x8 __attribute__((ext_vector_type(8)));
typedef float f32x4  __attribute__((ext_vector_type(4)));

__device__ __forceinline__ float bf2f(unsigned short u){
  union { unsigned int i; float f; } v; v.i = ((unsigned int)u) << 16; return v.f;
}
__device__ __forceinline__ unsigned short f2bf(float f){
  union { float f; unsigned int i; } v; v.f = f;
  unsigned int x = v.i;
  return (unsigned short)((x + 0x7fffu + ((x >> 16) & 1u)) >> 16); // RNE
}

// ---- prep: transpose to k8-major + atomic-free bucketing (unchanged) ------

__global__ __launch_bounds__(256) void prep_k(
    const float* __restrict__ Wh, const float* __restrict__ W0,
    const int* __restrict__ midx,
    unsigned short* __restrict__ Wth, unsigned short* __restrict__ Wt0,
    int* __restrict__ segcnt, int* __restrict__ bucket){
  int bid = blockIdx.x, tid = threadIdx.x;
  if (bid < 192){
    __shared__ __align__(16) unsigned short tile[64 * LSTR];
    int mat = bid >> 2, ck = bid & 3;
    const float* src = Wh + (size_t)mat * 65536 + (size_t)ck * 64 * 256;
    int r = tid >> 2, seg = (tid & 3) * 64;
    const float* sp = &src[r * 256 + seg];
    #pragma unroll
    for (int j8 = 0; j8 < 8; j8++){
      float4 f0 = *(const float4*)&sp[j8 * 8];
      float4 f1 = *(const float4*)&sp[j8 * 8 + 4];
      __align__(16) unsigned short t8[8];
      t8[0]=f2bf(f0.x); t8[1]=f2bf(f0.y); t8[2]=f2bf(f0.z); t8[3]=f2bf(f0.w);
      t8[4]=f2bf(f1.x); t8[5]=f2bf(f1.y); t8[6]=f2bf(f1.z); t8[7]=f2bf(f1.w);
      *(uint4*)&tile[r * LSTR + seg + j8 * 8] = *(const uint4*)t8;
    }
    __syncthreads();
    unsigned short* dst = Wth + (size_t)mat * 65536 + (size_t)ck * 16384;
    #pragma unroll
    for (int it = 0; it < 8; it++){
      int s = it * 256 + tid;
      int k8l = s >> 8, n = s & 255;
      __align__(16) unsigned short t8[8];
      #pragma unroll
      for (int j = 0; j < 8; j++) t8[j] = tile[(k8l * 8 + j) * LSTR + n];
      *(uint4*)&dst[(size_t)s * 8] = *(const uint4*)t8;
    }
  } else if (bid < 200){
    int c = bid - 192;
    #pragma unroll
    for (int it = 0; it < 4; it++){
      int s = it * 256 + tid;
      int k8 = s >> 8, n = s & 255;
      __align__(16) unsigned short t8[8];
      #pragma unroll
      for (int j = 0; j < 8; j++){
        int k = k8 * 8 + j;
        t8[j] = (k < 29) ? f2bf(W0[(c * 29 + k) * 256 + n]) : (unsigned short)0;
      }
      *(uint4*)&Wt0[(size_t)c * 8192 + (size_t)s * 8] = *(const uint4*)t8;
    }
  } else {
    __shared__ int cur[NCH];
    int sb = bid - 200;
    int lane = tid & 63;
    if (tid < NCH) cur[tid] = 0;
    __syncthreads();
    for (int it = 0; it < 8; it++){
      int i = sb * PSEG + it * 256 + tid;
      int c = midx[i];
      #pragma unroll
      for (int cc = 0; cc < NCH; cc++){
        unsigned long long m = __ballot(c == cc);
        if (!m) continue;
        int leader = (int)(__ffsll((long long)m) - 1);
        int wb = 0;
        if (lane == leader) wb = atomicAdd(&cur[cc], (int)__popcll(m));
        wb = __shfl(wb, leader);
        if (c == cc){
          int rk = (int)__popcll(m & ((1ull << lane) - 1));
          bucket[cc * SEG + sb * PSEG + wb + rk] = i;
        }
      }
    }
    __syncthreads();
    if (tid < NCH) segcnt[sb * NCH + tid] = cur[tid];
  }
}

// ---- main fused MLP: rolling 1-ahead B prefetch, bf16 bias, MT=32 ---------

__global__ __launch_bounds__(256) void mlp_k(
    const float* __restrict__ x,
    const float* __restrict__ proc,
    const float* __restrict__ b0,
    const float* __restrict__ bh,
    const float* __restrict__ Wl,
    const float* __restrict__ bl,
    const unsigned short* __restrict__ Wt0,
    const unsigned short* __restrict__ Wth,
    const int* __restrict__ segcnt,
    const int* __restrict__ bucket,
    float* __restrict__ out)
{
  __shared__ __align__(16) unsigned short actA[MT * LSTR];
  __shared__ __align__(16) unsigned short actB[MT * LSTR];
  __shared__ unsigned short biasb[7 * 256];   // bf16
  __shared__ unsigned short wlb[512];         // bf16
  __shared__ int ridx[MT];

  int chart = blockIdx.x & 7;     // XCD swizzle
  int tile  = blockIdx.x >> 3;

  int pre[9];
  pre[0] = 0;
  #pragma unroll
  for (int s = 0; s < 8; s++) pre[s + 1] = pre[s] + segcnt[s * NCH + chart];
  int total = pre[8];
  int cnt = total - tile * MT;
  if (cnt <= 0) return;
  if (cnt > MT) cnt = MT;

  int tid  = threadIdx.x;
  int lane = tid & 63;
  int wv   = tid >> 6;
  int l15  = lane & 15;
  int quad = lane >> 4;
  int cb   = wv * 64;             // wave's output-column base (N-split)

  // stage biases + Wl (bf16)
  biasb[tid] = f2bf(b0[chart * 256 + tid]);
  #pragma unroll
  for (int j = 0; j < 6; j++)
    biasb[(j + 1) * 256 + tid] = f2bf(bh[(chart * 6 + j) * 256 + tid]);
  wlb[tid]       = f2bf(Wl[chart * 512 + tid]);
  wlb[256 + tid] = f2bf(Wl[chart * 512 + 256 + tid]);

  // positional encoding -> actA
  if (tid < MT){
    int row = tid;
    int g = -1;
    if (row < cnt){
      int r = tile * MT + row;
      int sb = 0, off = 0;
      #pragma unroll
      for (int s = 0; s < 8; s++)
        if (r >= pre[s]){ sb = s; off = r - pre[s]; }
      g = bucket[chart * SEG + sb * PSEG + off];
    }
    ridx[row] = g;
    unsigned short* rowp = &actA[row * LSTR];
    if (g >= 0){
      float xv0 = x[g*3+0], xv1 = x[g*3+1], xv2 = x[g*3+2];
      rowp[0] = f2bf(xv0); rowp[1] = f2bf(xv1); rowp[2] = f2bf(xv2);
      #pragma unroll
      for (int d = 1; d <= 4; d++){
        float s = (float)(1 << d) * 3.14159265358979323846f;
        int o = 3 + (d - 1) * 6;
        rowp[o+0] = f2bf(sinf(s*xv0)); rowp[o+1] = f2bf(sinf(s*xv1)); rowp[o+2] = f2bf(sinf(s*xv2));
        rowp[o+3] = f2bf(cosf(s*xv0)); rowp[o+4] = f2bf(cosf(s*xv1)); rowp[o+5] = f2bf(cosf(s*xv2));
      }
      rowp[27] = f2bf(proc[0]); rowp[28] = f2bf(proc[1]);
      rowp[29] = 0; rowp[30] = 0; rowp[31] = 0;
    } else {
      #pragma unroll
      for (int k = 0; k < 32; k++) rowp[k] = 0;
    }
  }
  __syncthreads();

  f32x4 acc[2][4];
  const f32x4 zz = {0.f, 0.f, 0.f, 0.f};

  // Layer 0: (32x32)@(32x256)
  {
    const unsigned short* W0p = Wt0 + chart * 8192;
    bf16x8 b0r[4];
    #pragma unroll
    for (int nt = 0; nt < 4; nt++)
      b0r[nt] = *(const bf16x8*)&W0p[(size_t)(quad * 256 + cb + nt * 16 + l15) * 8];
    #pragma unroll
    for (int mt = 0; mt < 2; mt++){
      bf16x8 a0 = *(const bf16x8*)&actA[(mt * 16 + l15) * LSTR + quad * 8];
      #pragma unroll
      for (int nt = 0; nt < 4; nt++)
        acc[mt][nt] = __builtin_amdgcn_mfma_f32_16x16x32_bf16(a0, b0r[nt], zz, 0, 0, 0);
    }
    #pragma unroll
    for (int nt = 0; nt < 4; nt++){
      int col = cb + nt * 16 + l15;
      float bias = bf2f(biasb[col]);
      #pragma unroll
      for (int mt = 0; mt < 2; mt++)
        #pragma unroll
        for (int r = 0; r < 4; r++){
          float v = acc[mt][nt][r] + bias;
          v = v > 0.f ? v : 0.f;
          actB[(mt * 16 + quad * 4 + r) * LSTR + col] = f2bf(v);
        }
    }
  }
  __syncthreads();

  // 6 hidden layers: rolling 1-group-ahead B prefetch (source-order early issue)
  for (int l = 1; l <= 6; l++){
    const unsigned short* wl8 = Wth + ((size_t)(chart * 6 + l - 1) << 16)
                              + (size_t)(cb + l15) * 8 + (size_t)quad * 2048;
    const unsigned short* ain = (l & 1) ? actB : actA;
    unsigned short* aout      = (l & 1) ? actA : actB;

    bf16x8 bcur[4], bnxt[4];
    #pragma unroll
    for (int nt = 0; nt < 4; nt++)
      bcur[nt] = *(const bf16x8*)&wl8[(size_t)nt * 128];

    #pragma unroll
    for (int kk = 0; kk < 8; kk++){
      // issue next k-group's loads BEFORE this group's MFMAs
      if (kk < 7){
        const unsigned short* wn = wl8 + (size_t)(kk + 1) * 8192;
        #pragma unroll
        for (int nt = 0; nt < 4; nt++)
          bnxt[nt] = *(const bf16x8*)&wn[(size_t)nt * 128];
      }
      bf16x8 a0 = *(const bf16x8*)&ain[(0 * 16 + l15) * LSTR + kk * 32 + quad * 8];
      bf16x8 a1 = *(const bf16x8*)&ain[(1 * 16 + l15) * LSTR + kk * 32 + quad * 8];
      #pragma unroll
      for (int nt = 0; nt < 4; nt++){
        acc[0][nt] = __builtin_amdgcn_mfma_f32_16x16x32_bf16(
            a0, bcur[nt], (kk == 0) ? zz : acc[0][nt], 0, 0, 0);
        acc[1][nt] = __builtin_amdgcn_mfma_f32_16x16x32_bf16(
            a1, bcur[nt], (kk == 0) ? zz : acc[1][nt], 0, 0, 0);
      }
      #pragma unroll
      for (int nt = 0; nt < 4; nt++) bcur[nt] = bnxt[nt];
    }

    #pragma unroll
    for (int nt = 0; nt < 4; nt++){
      int col = cb + nt * 16 + l15;
      float bias = bf2f(biasb[l * 256 + col]);
      #pragma unroll
      for (int mt = 0; mt < 2; mt++)
        #pragma unroll
        for (int r = 0; r < 4; r++){
          float v = acc[mt][nt][r] + bias;
          v = v > 0.f ? v : 0.f;
          aout[(mt * 16 + quad * 4 + r) * LSTR + col] = f2bf(v);
        }
    }
    __syncthreads();
  }

  // Final layer: (32x256)@(256x2) + sigmoid; layer-6 output in actB
  {
    int m = tid >> 3;          // 0..31 rows
    int p = tid & 7;           // 8 threads/row, 32 k each
    const unsigned short* hrow = actB + m * LSTR + p * 32;
    const unsigned short* wlp = wlb + p * 64;
    float s0 = 0.f, s1 = 0.f;
    #pragma unroll 8
    for (int k = 0; k < 32; k += 2){
      unsigned int w01 = *(const unsigned int*)&wlp[k * 2];
      unsigned int w23 = *(const unsigned int*)&wlp[k * 2 + 2];
      unsigned int h2  = *(const unsigned int*)&hrow[k];
      float hv0 = bf2f((unsigned short)(h2 & 0xffff));
      float hv1 = bf2f((unsigned short)(h2 >> 16));
      s0 += hv0 * bf2f((unsigned short)(w01 & 0xffff)) + hv1 * bf2f((unsigned short)(w23 & 0xffff));
      s1 += hv0 * bf2f((unsigned short)(w01 >> 16))    + hv1 * bf2f((unsigned short)(w23 >> 16));
    }
    s0 += __shfl_xor(s0, 1); s0 += __shfl_xor(s0, 2); s0 += __shfl_xor(s0, 4);
    s1 += __shfl_xor(s1, 1); s1 += __shfl_xor(s1, 2); s1 += __shfl_xor(s1, 4);
    if (p == 0){
      int g = ridx[m];
      if (g >= 0){
        float o0 = 1.f / (1.f + __expf(-(s0 + bl[chart*2+0])));
        float o1 = 1.f / (1.f + __expf(-(s1 + bl[chart*2+1])));
        *(float2*)&out[(size_t)g * 2] = make_float2(o0, o1);
      }
    }
  }
}

// ---- launch ---------------------------------------------------------------

extern "C" void kernel_launch(void* const* d_in, const int* in_sizes, int n_in,
                              void* d_out, int out_size, void* d_ws, size_t ws_size,
                              hipStream_t stream){
  const float* x    = (const float*)d_in[0];
  const float* proc = (const float*)d_in[1];
  const float* W0   = (const float*)d_in[2];
  const float* b0   = (const float*)d_in[3];
  const float* Wh   = (const float*)d_in[4];
  const float* bh   = (const float*)d_in[5];
  const float* Wl   = (const float*)d_in[6];
  const float* bl   = (const float*)d_in[7];
  const int* midx = (const int*)d_in[8];
  float* out = (float*)d_out;

  char* ws = (char*)d_ws;
  int* segcnt = (int*)ws;                           // 8 segs x 8 charts
  int* bucket = segcnt + 64;                        // NCH * SEG ints
  size_t off = (((size_t)(64 + NCH * SEG)) * 4 + 15) & ~(size_t)15;
  unsigned short* Wt0 = (unsigned short*)(ws + off);  // 8 * 8192 bf16
  unsigned short* Wth = Wt0 + NCH * 8192;             // 8 * 6 * 65536 bf16

  hipLaunchKernelGGL(prep_k, dim3(208),  dim3(256), 0, stream,
                     Wh, W0, midx, Wth, Wt0, segcnt, bucket);
  hipLaunchKernelGGL(mlp_k,  dim3(4096), dim3(256), 0, stream,
                     x, proc, b0, bh, Wl, bl, Wt0, Wth, segcnt, bucket, out);
}

// Round 15
// 128.550 us; speedup vs baseline: 1.0247x; 1.0247x over previous
//
#include <hip/hip_runtime.h>
#include <hip/hip_bf16.h>
#include <math.h>

#define NPTS   16384
#define NCH    8
#define MT     32    // rows per block
#define LSTR   264   // act row stride (ushort)
#define SEG    16384 // fixed bucket segment per chart
#define PSEG   2048  // points per scatter sub-segment

typedef short bf16x8 __attribute__((ext_vector_type(8)));
typedef float f32x4  __attribute__((ext_vector_type(4)));

__device__ __forceinline__ float bf2f(unsigned short u){
  union { unsigned int i; float f; } v; v.i = ((unsigned int)u) << 16; return v.f;
}
__device__ __forceinline__ unsigned short f2bf(float f){
  union { float f; unsigned int i; } v; v.f = f;
  unsigned int x = v.i;
  return (unsigned short)((x + 0x7fffu + ((x >> 16) & 1u)) >> 16); // RNE
}

// ---- prep: transpose to k8-major + atomic-free bucketing (unchanged) ------

__global__ __launch_bounds__(256) void prep_k(
    const float* __restrict__ Wh, const float* __restrict__ W0,
    const int* __restrict__ midx,
    unsigned short* __restrict__ Wth, unsigned short* __restrict__ Wt0,
    int* __restrict__ segcnt, int* __restrict__ bucket){
  int bid = blockIdx.x, tid = threadIdx.x;
  if (bid < 192){
    __shared__ __align__(16) unsigned short tile[64 * LSTR];
    int mat = bid >> 2, ck = bid & 3;
    const float* src = Wh + (size_t)mat * 65536 + (size_t)ck * 64 * 256;
    int r = tid >> 2, seg = (tid & 3) * 64;
    const float* sp = &src[r * 256 + seg];
    #pragma unroll
    for (int j8 = 0; j8 < 8; j8++){
      float4 f0 = *(const float4*)&sp[j8 * 8];
      float4 f1 = *(const float4*)&sp[j8 * 8 + 4];
      __align__(16) unsigned short t8[8];
      t8[0]=f2bf(f0.x); t8[1]=f2bf(f0.y); t8[2]=f2bf(f0.z); t8[3]=f2bf(f0.w);
      t8[4]=f2bf(f1.x); t8[5]=f2bf(f1.y); t8[6]=f2bf(f1.z); t8[7]=f2bf(f1.w);
      *(uint4*)&tile[r * LSTR + seg + j8 * 8] = *(const uint4*)t8;
    }
    __syncthreads();
    unsigned short* dst = Wth + (size_t)mat * 65536 + (size_t)ck * 16384;
    #pragma unroll
    for (int it = 0; it < 8; it++){
      int s = it * 256 + tid;
      int k8l = s >> 8, n = s & 255;
      __align__(16) unsigned short t8[8];
      #pragma unroll
      for (int j = 0; j < 8; j++) t8[j] = tile[(k8l * 8 + j) * LSTR + n];
      *(uint4*)&dst[(size_t)s * 8] = *(const uint4*)t8;
    }
  } else if (bid < 200){
    int c = bid - 192;
    #pragma unroll
    for (int it = 0; it < 4; it++){
      int s = it * 256 + tid;
      int k8 = s >> 8, n = s & 255;
      __align__(16) unsigned short t8[8];
      #pragma unroll
      for (int j = 0; j < 8; j++){
        int k = k8 * 8 + j;
        t8[j] = (k < 29) ? f2bf(W0[(c * 29 + k) * 256 + n]) : (unsigned short)0;
      }
      *(uint4*)&Wt0[(size_t)c * 8192 + (size_t)s * 8] = *(const uint4*)t8;
    }
  } else {
    __shared__ int cur[NCH];
    int sb = bid - 200;
    int lane = tid & 63;
    if (tid < NCH) cur[tid] = 0;
    __syncthreads();
    for (int it = 0; it < 8; it++){
      int i = sb * PSEG + it * 256 + tid;
      int c = midx[i];
      #pragma unroll
      for (int cc = 0; cc < NCH; cc++){
        unsigned long long m = __ballot(c == cc);
        if (!m) continue;
        int leader = (int)(__ffsll((long long)m) - 1);
        int wb = 0;
        if (lane == leader) wb = atomicAdd(&cur[cc], (int)__popcll(m));
        wb = __shfl(wb, leader);
        if (c == cc){
          int rk = (int)__popcll(m & ((1ull << lane) - 1));
          bucket[cc * SEG + sb * PSEG + wb + rk] = i;
        }
      }
    }
    __syncthreads();
    if (tid < NCH) segcnt[sb * NCH + tid] = cur[tid];
  }
}

// ---- main fused MLP: asm-issued B slab + manual fine-grained vmcnt --------
// EARLY-CLOBBER (=&v) is essential: outputs must not overlap the address pair,
// since the first load retires before the later loads read %4. (r14 crash.)

#define LOADG(g) do {                                                          \
    const unsigned short* _p = wlane + (size_t)(g) * 8192;                     \
    asm volatile("global_load_dwordx4 %0, %4, off\n\t"                         \
                 "global_load_dwordx4 %1, %4, off offset:256\n\t"              \
                 "global_load_dwordx4 %2, %4, off offset:512\n\t"              \
                 "global_load_dwordx4 %3, %4, off offset:768"                  \
        : "=&v"(br[g][0]), "=&v"(br[g][1]), "=&v"(br[g][2]), "=&v"(br[g][3])   \
        : "v"(_p));                                                            \
  } while (0)

// wait until group g's loads retired (28-4g newer may remain in flight);
// +v operands pin the data dependence for the consuming MFMAs
#define WAITG(g, n)                                                            \
  asm volatile("s_waitcnt vmcnt(" #n ")"                                       \
      : "+v"(br[g][0]), "+v"(br[g][1]), "+v"(br[g][2]), "+v"(br[g][3]))

#define MFMAG(g)                                                               \
  {                                                                            \
    bf16x8 a0 = *(const bf16x8*)&ain[(l15) * LSTR + (g) * 32 + quad * 8];      \
    bf16x8 a1 = *(const bf16x8*)&ain[(16 + l15) * LSTR + (g) * 32 + quad * 8]; \
    _Pragma("unroll")                                                          \
    for (int nt = 0; nt < 4; nt++){                                            \
      acc[0][nt] = __builtin_amdgcn_mfma_f32_16x16x32_bf16(                    \
          a0, br[g][nt], ((g) == 0) ? zz : acc[0][nt], 0, 0, 0);               \
      acc[1][nt] = __builtin_amdgcn_mfma_f32_16x16x32_bf16(                    \
          a1, br[g][nt], ((g) == 0) ? zz : acc[1][nt], 0, 0, 0);               \
    }                                                                          \
  }

__global__ __launch_bounds__(256) void mlp_k(
    const float* __restrict__ x,
    const float* __restrict__ proc,
    const float* __restrict__ b0,
    const float* __restrict__ bh,
    const float* __restrict__ Wl,
    const float* __restrict__ bl,
    const unsigned short* __restrict__ Wt0,
    const unsigned short* __restrict__ Wth,
    const int* __restrict__ segcnt,
    const int* __restrict__ bucket,
    float* __restrict__ out)
{
  __shared__ __align__(16) unsigned short actA[MT * LSTR];
  __shared__ __align__(16) unsigned short actB[MT * LSTR];
  __shared__ unsigned short biasb[7 * 256];   // bf16
  __shared__ unsigned short wlb[512];         // bf16
  __shared__ int ridx[MT];

  int chart = blockIdx.x & 7;     // XCD swizzle
  int tile  = blockIdx.x >> 3;

  int pre[9];
  pre[0] = 0;
  #pragma unroll
  for (int s = 0; s < 8; s++) pre[s + 1] = pre[s] + segcnt[s * NCH + chart];
  int total = pre[8];
  int cnt = total - tile * MT;
  if (cnt <= 0) return;
  if (cnt > MT) cnt = MT;

  int tid  = threadIdx.x;
  int lane = tid & 63;
  int wv   = tid >> 6;
  int l15  = lane & 15;
  int quad = lane >> 4;
  int cb   = wv * 64;             // wave's output-column base (N-split)

  // stage biases + Wl (bf16)
  biasb[tid] = f2bf(b0[chart * 256 + tid]);
  #pragma unroll
  for (int j = 0; j < 6; j++)
    biasb[(j + 1) * 256 + tid] = f2bf(bh[(chart * 6 + j) * 256 + tid]);
  wlb[tid]       = f2bf(Wl[chart * 512 + tid]);
  wlb[256 + tid] = f2bf(Wl[chart * 512 + 256 + tid]);

  // positional encoding -> actA
  if (tid < MT){
    int row = tid;
    int g = -1;
    if (row < cnt){
      int r = tile * MT + row;
      int sb = 0, off = 0;
      #pragma unroll
      for (int s = 0; s < 8; s++)
        if (r >= pre[s]){ sb = s; off = r - pre[s]; }
      g = bucket[chart * SEG + sb * PSEG + off];
    }
    ridx[row] = g;
    unsigned short* rowp = &actA[row * LSTR];
    if (g >= 0){
      float xv0 = x[g*3+0], xv1 = x[g*3+1], xv2 = x[g*3+2];
      rowp[0] = f2bf(xv0); rowp[1] = f2bf(xv1); rowp[2] = f2bf(xv2);
      #pragma unroll
      for (int d = 1; d <= 4; d++){
        float s = (float)(1 << d) * 3.14159265358979323846f;
        int o = 3 + (d - 1) * 6;
        rowp[o+0] = f2bf(sinf(s*xv0)); rowp[o+1] = f2bf(sinf(s*xv1)); rowp[o+2] = f2bf(sinf(s*xv2));
        rowp[o+3] = f2bf(cosf(s*xv0)); rowp[o+4] = f2bf(cosf(s*xv1)); rowp[o+5] = f2bf(cosf(s*xv2));
      }
      rowp[27] = f2bf(proc[0]); rowp[28] = f2bf(proc[1]);
      rowp[29] = 0; rowp[30] = 0; rowp[31] = 0;
    } else {
      #pragma unroll
      for (int k = 0; k < 32; k++) rowp[k] = 0;
    }
  }
  __syncthreads();

  f32x4 acc[2][4];
  const f32x4 zz = {0.f, 0.f, 0.f, 0.f};

  // Layer 0: (32x32)@(32x256)
  {
    const unsigned short* W0p = Wt0 + chart * 8192;
    bf16x8 b0r[4];
    #pragma unroll
    for (int nt = 0; nt < 4; nt++)
      b0r[nt] = *(const bf16x8*)&W0p[(size_t)(quad * 256 + cb + nt * 16 + l15) * 8];
    #pragma unroll
    for (int mt = 0; mt < 2; mt++){
      bf16x8 a0 = *(const bf16x8*)&actA[(mt * 16 + l15) * LSTR + quad * 8];
      #pragma unroll
      for (int nt = 0; nt < 4; nt++)
        acc[mt][nt] = __builtin_amdgcn_mfma_f32_16x16x32_bf16(a0, b0r[nt], zz, 0, 0, 0);
    }
    #pragma unroll
    for (int nt = 0; nt < 4; nt++){
      int col = cb + nt * 16 + l15;
      float bias = bf2f(biasb[col]);
      #pragma unroll
      for (int mt = 0; mt < 2; mt++)
        #pragma unroll
        for (int r = 0; r < 4; r++){
          float v = acc[mt][nt][r] + bias;
          v = v > 0.f ? v : 0.f;
          actB[(mt * 16 + quad * 4 + r) * LSTR + col] = f2bf(v);
        }
    }
  }
  __syncthreads();

  // 6 hidden layers: asm-issued full-layer slab, fine-grained vmcnt consume
  for (int l = 1; l <= 6; l++){
    const unsigned short* wlane = Wth + ((size_t)(chart * 6 + l - 1) << 16)
                                + (size_t)(quad * 256 + cb + l15) * 8;
    const unsigned short* ain = (l & 1) ? actB : actA;
    unsigned short* aout      = (l & 1) ? actA : actB;

    bf16x8 br[8][4];
    LOADG(0); LOADG(1); LOADG(2); LOADG(3);
    LOADG(4); LOADG(5); LOADG(6); LOADG(7);

    WAITG(0, 28); MFMAG(0);
    WAITG(1, 24); MFMAG(1);
    WAITG(2, 20); MFMAG(2);
    WAITG(3, 16); MFMAG(3);
    WAITG(4, 12); MFMAG(4);
    WAITG(5, 8);  MFMAG(5);
    WAITG(6, 4);  MFMAG(6);
    WAITG(7, 0);  MFMAG(7);

    #pragma unroll
    for (int nt = 0; nt < 4; nt++){
      int col = cb + nt * 16 + l15;
      float bias = bf2f(biasb[l * 256 + col]);
      #pragma unroll
      for (int mt = 0; mt < 2; mt++)
        #pragma unroll
        for (int r = 0; r < 4; r++){
          float v = acc[mt][nt][r] + bias;
          v = v > 0.f ? v : 0.f;
          aout[(mt * 16 + quad * 4 + r) * LSTR + col] = f2bf(v);
        }
    }
    __syncthreads();
  }

  // Final layer: (32x256)@(256x2) + sigmoid; layer-6 output in actB
  {
    int m = tid >> 3;
    int p = tid & 7;
    const unsigned short* hrow = actB + m * LSTR + p * 32;
    const unsigned short* wlp = wlb + p * 64;
    float s0 = 0.f, s1 = 0.f;
    #pragma unroll 8
    for (int k = 0; k < 32; k += 2){
      unsigned int w01 = *(const unsigned int*)&wlp[k * 2];
      unsigned int w23 = *(const unsigned int*)&wlp[k * 2 + 2];
      unsigned int h2  = *(const unsigned int*)&hrow[k];
      float hv0 = bf2f((unsigned short)(h2 & 0xffff));
      float hv1 = bf2f((unsigned short)(h2 >> 16));
      s0 += hv0 * bf2f((unsigned short)(w01 & 0xffff)) + hv1 * bf2f((unsigned short)(w23 & 0xffff));
      s1 += hv0 * bf2f((unsigned short)(w01 >> 16))    + hv1 * bf2f((unsigned short)(w23 >> 16));
    }
    s0 += __shfl_xor(s0, 1); s0 += __shfl_xor(s0, 2); s0 += __shfl_xor(s0, 4);
    s1 += __shfl_xor(s1, 1); s1 += __shfl_xor(s1, 2); s1 += __shfl_xor(s1, 4);
    if (p == 0){
      int g = ridx[m];
      if (g >= 0){
        float o0 = 1.f / (1.f + __expf(-(s0 + bl[chart*2+0])));
        float o1 = 1.f / (1.f + __expf(-(s1 + bl[chart*2+1])));
        *(float2*)&out[(size_t)g * 2] = make_float2(o0, o1);
      }
    }
  }
}

// ---- launch ---------------------------------------------------------------

extern "C" void kernel_launch(void* const* d_in, const int* in_sizes, int n_in,
                              void* d_out, int out_size, void* d_ws, size_t ws_size,
                              hipStream_t stream){
  const float* x    = (const float*)d_in[0];
  const float* proc = (const float*)d_in[1];
  const float* W0   = (const float*)d_in[2];
  const float* b0   = (const float*)d_in[3];
  const float* Wh   = (const float*)d_in[4];
  const float* bh   = (const float*)d_in[5];
  const float* Wl   = (const float*)d_in[6];
  const float* bl   = (const float*)d_in[7];
  const int* midx = (const int*)d_in[8];
  float* out = (float*)d_out;

  char* ws = (char*)d_ws;
  int* segcnt = (int*)ws;                           // 8 segs x 8 charts
  int* bucket = segcnt + 64;                        // NCH * SEG ints
  size_t off = (((size_t)(64 + NCH * SEG)) * 4 + 15) & ~(size_t)15;
  unsigned short* Wt0 = (unsigned short*)(ws + off);  // 8 * 8192 bf16
  unsigned short* Wth = Wt0 + NCH * 8192;             // 8 * 6 * 65536 bf16

  hipLaunchKernelGGL(prep_k, dim3(208),  dim3(256), 0, stream,
                     Wh, W0, midx, Wth, Wt0, segcnt, bucket);
  hipLaunchKernelGGL(mlp_k,  dim3(4096), dim3(256), 0, stream,
                     x, proc, b0, bh, Wl, bl, Wt0, Wth, segcnt, bucket, out);
}

// Round 16
// 120.454 us; speedup vs baseline: 1.0935x; 1.0672x over previous
//
#include <hip/hip_runtime.h>
#include <hip/hip_bf16.h>
#include <math.h>

#define NPTS   16384
#define NCH    8
#define MT     64    // rows per block
#define LSTR   264   // act row stride (ushort)
#define SEG    16384 // fixed bucket segment per chart
#define PSEG   2048  // points per scatter sub-segment

typedef short bf16x8 __attribute__((ext_vector_type(8)));
typedef float f32x4  __attribute__((ext_vector_type(4)));

__device__ __forceinline__ float bf2f(unsigned short u){
  union { unsigned int i; float f; } v; v.i = ((unsigned int)u) << 16; return v.f;
}
__device__ __forceinline__ unsigned short f2bf(float f){
  union { float f; unsigned int i; } v; v.f = f;
  unsigned int x = v.i;
  return (unsigned short)((x + 0x7fffu + ((x >> 16) & 1u)) >> 16); // RNE
}

// ---- prep: transpose to k8-major + atomic-free bucketing (unchanged) ------

__global__ __launch_bounds__(256) void prep_k(
    const float* __restrict__ Wh, const float* __restrict__ W0,
    const int* __restrict__ midx,
    unsigned short* __restrict__ Wth, unsigned short* __restrict__ Wt0,
    int* __restrict__ segcnt, int* __restrict__ bucket){
  int bid = blockIdx.x, tid = threadIdx.x;
  if (bid < 192){
    __shared__ __align__(16) unsigned short tile[64 * LSTR];
    int mat = bid >> 2, ck = bid & 3;
    const float* src = Wh + (size_t)mat * 65536 + (size_t)ck * 64 * 256;
    int r = tid >> 2, seg = (tid & 3) * 64;
    const float* sp = &src[r * 256 + seg];
    #pragma unroll
    for (int j8 = 0; j8 < 8; j8++){
      float4 f0 = *(const float4*)&sp[j8 * 8];
      float4 f1 = *(const float4*)&sp[j8 * 8 + 4];
      __align__(16) unsigned short t8[8];
      t8[0]=f2bf(f0.x); t8[1]=f2bf(f0.y); t8[2]=f2bf(f0.z); t8[3]=f2bf(f0.w);
      t8[4]=f2bf(f1.x); t8[5]=f2bf(f1.y); t8[6]=f2bf(f1.z); t8[7]=f2bf(f1.w);
      *(uint4*)&tile[r * LSTR + seg + j8 * 8] = *(const uint4*)t8;
    }
    __syncthreads();
    unsigned short* dst = Wth + (size_t)mat * 65536 + (size_t)ck * 16384;
    #pragma unroll
    for (int it = 0; it < 8; it++){
      int s = it * 256 + tid;
      int k8l = s >> 8, n = s & 255;
      __align__(16) unsigned short t8[8];
      #pragma unroll
      for (int j = 0; j < 8; j++) t8[j] = tile[(k8l * 8 + j) * LSTR + n];
      *(uint4*)&dst[(size_t)s * 8] = *(const uint4*)t8;
    }
  } else if (bid < 200){
    int c = bid - 192;
    #pragma unroll
    for (int it = 0; it < 4; it++){
      int s = it * 256 + tid;
      int k8 = s >> 8, n = s & 255;
      __align__(16) unsigned short t8[8];
      #pragma unroll
      for (int j = 0; j < 8; j++){
        int k = k8 * 8 + j;
        t8[j] = (k < 29) ? f2bf(W0[(c * 29 + k) * 256 + n]) : (unsigned short)0;
      }
      *(uint4*)&Wt0[(size_t)c * 8192 + (size_t)s * 8] = *(const uint4*)t8;
    }
  } else {
    __shared__ int cur[NCH];
    int sb = bid - 200;
    int lane = tid & 63;
    if (tid < NCH) cur[tid] = 0;
    __syncthreads();
    for (int it = 0; it < 8; it++){
      int i = sb * PSEG + it * 256 + tid;
      int c = midx[i];
      #pragma unroll
      for (int cc = 0; cc < NCH; cc++){
        unsigned long long m = __ballot(c == cc);
        if (!m) continue;
        int leader = (int)(__ffsll((long long)m) - 1);
        int wb = 0;
        if (lane == leader) wb = atomicAdd(&cur[cc], (int)__popcll(m));
        wb = __shfl(wb, leader);
        if (c == cc){
          int rk = (int)__popcll(m & ((1ull << lane) - 1));
          bucket[cc * SEG + sb * PSEG + wb + rk] = i;
        }
      }
    }
    __syncthreads();
    if (tid < NCH) segcnt[sb * NCH + tid] = cur[tid];
  }
}

// ---- main fused MLP: MT=64, 4-deep asm ring, fine-grained vmcnt -----------
// EARLY-CLOBBER (=&v): outputs must not overlap the address pair (r14 crash).

#define LOADG(slot, g) do {                                                    \
    const unsigned short* _p = wlane + (size_t)(g) * 8192;                     \
    asm volatile("global_load_dwordx4 %0, %4, off\n\t"                         \
                 "global_load_dwordx4 %1, %4, off offset:256\n\t"              \
                 "global_load_dwordx4 %2, %4, off offset:512\n\t"              \
                 "global_load_dwordx4 %3, %4, off offset:768"                  \
        : "=&v"(br[slot][0]), "=&v"(br[slot][1]),                              \
          "=&v"(br[slot][2]), "=&v"(br[slot][3])                               \
        : "v"(_p));                                                            \
  } while (0)

#define WAITG(slot, n)                                                         \
  asm volatile("s_waitcnt vmcnt(" #n ")"                                       \
      : "+v"(br[slot][0]), "+v"(br[slot][1]),                                  \
        "+v"(br[slot][2]), "+v"(br[slot][3]))

#define MFMAG(slot, g)                                                         \
  {                                                                            \
    _Pragma("unroll")                                                          \
    for (int mt = 0; mt < 4; mt++){                                            \
      bf16x8 a = *(const bf16x8*)&ain[(mt * 16 + l15) * LSTR + (g) * 32 + quad * 8]; \
      _Pragma("unroll")                                                        \
      for (int nt = 0; nt < 4; nt++)                                           \
        acc[mt][nt] = __builtin_amdgcn_mfma_f32_16x16x32_bf16(                 \
            a, br[slot][nt], ((g) == 0) ? zz : acc[mt][nt], 0, 0, 0);          \
    }                                                                          \
  }

__global__ __launch_bounds__(256, 1) void mlp_k(
    const float* __restrict__ x,
    const float* __restrict__ proc,
    const float* __restrict__ b0,
    const float* __restrict__ bh,
    const float* __restrict__ Wl,
    const float* __restrict__ bl,
    const unsigned short* __restrict__ Wt0,
    const unsigned short* __restrict__ Wth,
    const int* __restrict__ segcnt,
    const int* __restrict__ bucket,
    float* __restrict__ out)
{
  __shared__ __align__(16) unsigned short actA[MT * LSTR];
  __shared__ __align__(16) unsigned short actB[MT * LSTR];
  __shared__ unsigned short biasb[7 * 256];   // bf16
  __shared__ unsigned short wlb[512];         // bf16
  __shared__ int ridx[MT];

  int chart = blockIdx.x & 7;     // XCD swizzle
  int tile  = blockIdx.x >> 3;

  int pre[9];
  pre[0] = 0;
  #pragma unroll
  for (int s = 0; s < 8; s++) pre[s + 1] = pre[s] + segcnt[s * NCH + chart];
  int total = pre[8];
  int cnt = total - tile * MT;
  if (cnt <= 0) return;
  if (cnt > MT) cnt = MT;

  int tid  = threadIdx.x;
  int lane = tid & 63;
  int wv   = tid >> 6;
  int l15  = lane & 15;
  int quad = lane >> 4;
  int cb   = wv * 64;             // wave's output-column base (N-split)

  // stage biases + Wl (bf16)
  biasb[tid] = f2bf(b0[chart * 256 + tid]);
  #pragma unroll
  for (int j = 0; j < 6; j++)
    biasb[(j + 1) * 256 + tid] = f2bf(bh[(chart * 6 + j) * 256 + tid]);
  wlb[tid]       = f2bf(Wl[chart * 512 + tid]);
  wlb[256 + tid] = f2bf(Wl[chart * 512 + 256 + tid]);

  // positional encoding -> actA
  if (tid < MT){
    int row = tid;
    int g = -1;
    if (row < cnt){
      int r = tile * MT + row;
      int sb = 0, off = 0;
      #pragma unroll
      for (int s = 0; s < 8; s++)
        if (r >= pre[s]){ sb = s; off = r - pre[s]; }
      g = bucket[chart * SEG + sb * PSEG + off];
    }
    ridx[row] = g;
    unsigned short* rowp = &actA[row * LSTR];
    if (g >= 0){
      float xv0 = x[g*3+0], xv1 = x[g*3+1], xv2 = x[g*3+2];
      rowp[0] = f2bf(xv0); rowp[1] = f2bf(xv1); rowp[2] = f2bf(xv2);
      #pragma unroll
      for (int d = 1; d <= 4; d++){
        float s = (float)(1 << d) * 3.14159265358979323846f;
        int o = 3 + (d - 1) * 6;
        rowp[o+0] = f2bf(sinf(s*xv0)); rowp[o+1] = f2bf(sinf(s*xv1)); rowp[o+2] = f2bf(sinf(s*xv2));
        rowp[o+3] = f2bf(cosf(s*xv0)); rowp[o+4] = f2bf(cosf(s*xv1)); rowp[o+5] = f2bf(cosf(s*xv2));
      }
      rowp[27] = f2bf(proc[0]); rowp[28] = f2bf(proc[1]);
      rowp[29] = 0; rowp[30] = 0; rowp[31] = 0;
    } else {
      #pragma unroll
      for (int k = 0; k < 32; k++) rowp[k] = 0;
    }
  }
  __syncthreads();

  f32x4 acc[4][4];
  const f32x4 zz = {0.f, 0.f, 0.f, 0.f};

  // Layer 0: (64x32)@(32x256); B from Wt0 k8-major (k8 = quad)
  {
    const unsigned short* W0p = Wt0 + chart * 8192;
    bf16x8 b0r[4];
    #pragma unroll
    for (int nt = 0; nt < 4; nt++)
      b0r[nt] = *(const bf16x8*)&W0p[(size_t)(quad * 256 + cb + nt * 16 + l15) * 8];
    #pragma unroll
    for (int mt = 0; mt < 4; mt++){
      bf16x8 a0 = *(const bf16x8*)&actA[(mt * 16 + l15) * LSTR + quad * 8];
      #pragma unroll
      for (int nt = 0; nt < 4; nt++)
        acc[mt][nt] = __builtin_amdgcn_mfma_f32_16x16x32_bf16(a0, b0r[nt], zz, 0, 0, 0);
    }
    #pragma unroll
    for (int nt = 0; nt < 4; nt++){
      int col = cb + nt * 16 + l15;
      float bias = bf2f(biasb[col]);
      #pragma unroll
      for (int mt = 0; mt < 4; mt++)
        #pragma unroll
        for (int r = 0; r < 4; r++){
          float v = acc[mt][nt][r] + bias;
          v = v > 0.f ? v : 0.f;
          actB[(mt * 16 + quad * 4 + r) * LSTR + col] = f2bf(v);
        }
    }
  }
  __syncthreads();

  // 6 hidden layers: 4-deep ring of asm-issued k-groups
  for (int l = 1; l <= 6; l++){
    const unsigned short* wlane = Wth + ((size_t)(chart * 6 + l - 1) << 16)
                                + (size_t)(quad * 256 + cb + l15) * 8;
    const unsigned short* ain = (l & 1) ? actB : actA;
    unsigned short* aout      = (l & 1) ? actA : actB;

    bf16x8 br[4][4];
    LOADG(0, 0); LOADG(1, 1); LOADG(2, 2); LOADG(3, 3);   // 16 in flight

    WAITG(0, 12); MFMAG(0, 0); LOADG(0, 4);
    WAITG(1, 12); MFMAG(1, 1); LOADG(1, 5);
    WAITG(2, 12); MFMAG(2, 2); LOADG(2, 6);
    WAITG(3, 12); MFMAG(3, 3); LOADG(3, 7);
    WAITG(0, 12); MFMAG(0, 4);
    WAITG(1, 8);  MFMAG(1, 5);
    WAITG(2, 4);  MFMAG(2, 6);
    WAITG(3, 0);  MFMAG(3, 7);

    #pragma unroll
    for (int nt = 0; nt < 4; nt++){
      int col = cb + nt * 16 + l15;
      float bias = bf2f(biasb[l * 256 + col]);
      #pragma unroll
      for (int mt = 0; mt < 4; mt++)
        #pragma unroll
        for (int r = 0; r < 4; r++){
          float v = acc[mt][nt][r] + bias;
          v = v > 0.f ? v : 0.f;
          aout[(mt * 16 + quad * 4 + r) * LSTR + col] = f2bf(v);
        }
    }
    __syncthreads();
  }

  // Final layer: (64x256)@(256x2) + sigmoid; layer-6 output in actB
  {
    int m = tid >> 2;          // 0..63 rows
    int p = tid & 3;           // 4 threads/row, 64 k each
    const unsigned short* hrow = actB + m * LSTR + p * 64;
    const unsigned short* wlp = wlb + p * 128;
    float s0 = 0.f, s1 = 0.f;
    #pragma unroll 8
    for (int k = 0; k < 64; k += 2){
      unsigned int w01 = *(const unsigned int*)&wlp[k * 2];
      unsigned int w23 = *(const unsigned int*)&wlp[k * 2 + 2];
      unsigned int h2  = *(const unsigned int*)&hrow[k];
      float hv0 = bf2f((unsigned short)(h2 & 0xffff));
      float hv1 = bf2f((unsigned short)(h2 >> 16));
      s0 += hv0 * bf2f((unsigned short)(w01 & 0xffff)) + hv1 * bf2f((unsigned short)(w23 & 0xffff));
      s1 += hv0 * bf2f((unsigned short)(w01 >> 16))    + hv1 * bf2f((unsigned short)(w23 >> 16));
    }
    s0 += __shfl_xor(s0, 1); s0 += __shfl_xor(s0, 2);
    s1 += __shfl_xor(s1, 1); s1 += __shfl_xor(s1, 2);
    if (p == 0){
      int g = ridx[m];
      if (g >= 0){
        float o0 = 1.f / (1.f + __expf(-(s0 + bl[chart*2+0])));
        float o1 = 1.f / (1.f + __expf(-(s1 + bl[chart*2+1])));
        *(float2*)&out[(size_t)g * 2] = make_float2(o0, o1);
      }
    }
  }
}

// ---- launch ---------------------------------------------------------------

extern "C" void kernel_launch(void* const* d_in, const int* in_sizes, int n_in,
                              void* d_out, int out_size, void* d_ws, size_t ws_size,
                              hipStream_t stream){
  const float* x    = (const float*)d_in[0];
  const float* proc = (const float*)d_in[1];
  const float* W0   = (const float*)d_in[2];
  const float* b0   = (const float*)d_in[3];
  const float* Wh   = (const float*)d_in[4];
  const float* bh   = (const float*)d_in[5];
  const float* Wl   = (const float*)d_in[6];
  const float* bl   = (const float*)d_in[7];
  const int* midx = (const int*)d_in[8];
  float* out = (float*)d_out;

  char* ws = (char*)d_ws;
  int* segcnt = (int*)ws;                           // 8 segs x 8 charts
  int* bucket = segcnt + 64;                        // NCH * SEG ints
  size_t off = (((size_t)(64 + NCH * SEG)) * 4 + 15) & ~(size_t)15;
  unsigned short* Wt0 = (unsigned short*)(ws + off);  // 8 * 8192 bf16
  unsigned short* Wth = Wt0 + NCH * 8192;             // 8 * 6 * 65536 bf16

  hipLaunchKernelGGL(prep_k, dim3(208),  dim3(256), 0, stream,
                     Wh, W0, midx, Wth, Wt0, segcnt, bucket);
  hipLaunchKernelGGL(mlp_k,  dim3(2048), dim3(256), 0, stream,
                     x, proc, b0, bh, Wl, bl, Wt0, Wth, segcnt, bucket, out);
}

// Round 17
// 120.161 us; speedup vs baseline: 1.0962x; 1.0024x over previous
//
#include <hip/hip_runtime.h>
#include <hip/hip_bf16.h>
#include <math.h>

#define NPTS   16384
#define NCH    8
#define MT     64    // rows per block
#define LSTR   264   // act row stride (ushort)
#define SEG    16384 // fixed bucket segment per chart
#define PSEG   2048  // points per scatter sub-segment

typedef short bf16x8 __attribute__((ext_vector_type(8)));
typedef float f32x4  __attribute__((ext_vector_type(4)));

__device__ __forceinline__ float bf2f(unsigned short u){
  union { unsigned int i; float f; } v; v.i = ((unsigned int)u) << 16; return v.f;
}
__device__ __forceinline__ unsigned short f2bf(float f){
  union { float f; unsigned int i; } v; v.f = f;
  unsigned int x = v.i;
  return (unsigned short)((x + 0x7fffu + ((x >> 16) & 1u)) >> 16); // RNE
}

// ---- prep: transpose to k8-major + atomic-free bucketing (unchanged) ------

__global__ __launch_bounds__(256) void prep_k(
    const float* __restrict__ Wh, const float* __restrict__ W0,
    const int* __restrict__ midx,
    unsigned short* __restrict__ Wth, unsigned short* __restrict__ Wt0,
    int* __restrict__ segcnt, int* __restrict__ bucket){
  int bid = blockIdx.x, tid = threadIdx.x;
  if (bid < 192){
    __shared__ __align__(16) unsigned short tile[64 * LSTR];
    int mat = bid >> 2, ck = bid & 3;
    const float* src = Wh + (size_t)mat * 65536 + (size_t)ck * 64 * 256;
    int r = tid >> 2, seg = (tid & 3) * 64;
    const float* sp = &src[r * 256 + seg];
    #pragma unroll
    for (int j8 = 0; j8 < 8; j8++){
      float4 f0 = *(const float4*)&sp[j8 * 8];
      float4 f1 = *(const float4*)&sp[j8 * 8 + 4];
      __align__(16) unsigned short t8[8];
      t8[0]=f2bf(f0.x); t8[1]=f2bf(f0.y); t8[2]=f2bf(f0.z); t8[3]=f2bf(f0.w);
      t8[4]=f2bf(f1.x); t8[5]=f2bf(f1.y); t8[6]=f2bf(f1.z); t8[7]=f2bf(f1.w);
      *(uint4*)&tile[r * LSTR + seg + j8 * 8] = *(const uint4*)t8;
    }
    __syncthreads();
    unsigned short* dst = Wth + (size_t)mat * 65536 + (size_t)ck * 16384;
    #pragma unroll
    for (int it = 0; it < 8; it++){
      int s = it * 256 + tid;
      int k8l = s >> 8, n = s & 255;
      __align__(16) unsigned short t8[8];
      #pragma unroll
      for (int j = 0; j < 8; j++) t8[j] = tile[(k8l * 8 + j) * LSTR + n];
      *(uint4*)&dst[(size_t)s * 8] = *(const uint4*)t8;
    }
  } else if (bid < 200){
    int c = bid - 192;
    #pragma unroll
    for (int it = 0; it < 4; it++){
      int s = it * 256 + tid;
      int k8 = s >> 8, n = s & 255;
      __align__(16) unsigned short t8[8];
      #pragma unroll
      for (int j = 0; j < 8; j++){
        int k = k8 * 8 + j;
        t8[j] = (k < 29) ? f2bf(W0[(c * 29 + k) * 256 + n]) : (unsigned short)0;
      }
      *(uint4*)&Wt0[(size_t)c * 8192 + (size_t)s * 8] = *(const uint4*)t8;
    }
  } else {
    __shared__ int cur[NCH];
    int sb = bid - 200;
    int lane = tid & 63;
    if (tid < NCH) cur[tid] = 0;
    __syncthreads();
    for (int it = 0; it < 8; it++){
      int i = sb * PSEG + it * 256 + tid;
      int c = midx[i];
      #pragma unroll
      for (int cc = 0; cc < NCH; cc++){
        unsigned long long m = __ballot(c == cc);
        if (!m) continue;
        int leader = (int)(__ffsll((long long)m) - 1);
        int wb = 0;
        if (lane == leader) wb = atomicAdd(&cur[cc], (int)__popcll(m));
        wb = __shfl(wb, leader);
        if (c == cc){
          int rk = (int)__popcll(m & ((1ull << lane) - 1));
          bucket[cc * SEG + sb * PSEG + wb + rk] = i;
        }
      }
    }
    __syncthreads();
    if (tid < NCH) segcnt[sb * NCH + tid] = cur[tid];
  }
}

// ---- main fused MLP: 512 threads / 8 waves, 32 cols per wave, asm slab ----
// EARLY-CLOBBER (=&v): outputs must not overlap the address pair (r14 crash).

#define LOADG(g) do {                                                          \
    const unsigned short* _p = wlane + (size_t)(g) * 8192;                     \
    asm volatile("global_load_dwordx4 %0, %2, off\n\t"                         \
                 "global_load_dwordx4 %1, %2, off offset:256"                  \
        : "=&v"(br[g][0]), "=&v"(br[g][1])                                     \
        : "v"(_p));                                                            \
  } while (0)

#define WAITG(g, n)                                                            \
  asm volatile("s_waitcnt vmcnt(" #n ")"                                       \
      : "+v"(br[g][0]), "+v"(br[g][1]))

#define MFMAG(g)                                                               \
  {                                                                            \
    _Pragma("unroll")                                                          \
    for (int mt = 0; mt < 4; mt++){                                            \
      bf16x8 a = *(const bf16x8*)&ain[(mt * 16 + l15) * LSTR + (g) * 32 + quad * 8]; \
      _Pragma("unroll")                                                        \
      for (int nt = 0; nt < 2; nt++)                                           \
        acc[mt][nt] = __builtin_amdgcn_mfma_f32_16x16x32_bf16(                 \
            a, br[g][nt], ((g) == 0) ? zz : acc[mt][nt], 0, 0, 0);             \
    }                                                                          \
  }

__global__ __launch_bounds__(512, 1) void mlp_k(
    const float* __restrict__ x,
    const float* __restrict__ proc,
    const float* __restrict__ b0,
    const float* __restrict__ bh,
    const float* __restrict__ Wl,
    const float* __restrict__ bl,
    const unsigned short* __restrict__ Wt0,
    const unsigned short* __restrict__ Wth,
    const int* __restrict__ segcnt,
    const int* __restrict__ bucket,
    float* __restrict__ out)
{
  __shared__ __align__(16) unsigned short actA[MT * LSTR];
  __shared__ __align__(16) unsigned short actB[MT * LSTR];
  __shared__ unsigned short biasb[7 * 256];   // bf16
  __shared__ unsigned short wlb[512];         // bf16
  __shared__ int ridx[MT];

  int chart = blockIdx.x & 7;     // XCD swizzle
  int tile  = blockIdx.x >> 3;

  int pre[9];
  pre[0] = 0;
  #pragma unroll
  for (int s = 0; s < 8; s++) pre[s + 1] = pre[s] + segcnt[s * NCH + chart];
  int total = pre[8];
  int cnt = total - tile * MT;
  if (cnt <= 0) return;
  if (cnt > MT) cnt = MT;

  int tid  = threadIdx.x;
  int lane = tid & 63;
  int wv   = tid >> 6;            // 0..7
  int l15  = lane & 15;
  int quad = lane >> 4;
  int cb   = wv * 32;             // wave's output-column base (32 cols/wave)

  // stage biases + Wl (bf16) -- first 256 threads only
  if (tid < 256){
    biasb[tid] = f2bf(b0[chart * 256 + tid]);
    #pragma unroll
    for (int j = 0; j < 6; j++)
      biasb[(j + 1) * 256 + tid] = f2bf(bh[(chart * 6 + j) * 256 + tid]);
    wlb[tid]       = f2bf(Wl[chart * 512 + tid]);
    wlb[256 + tid] = f2bf(Wl[chart * 512 + 256 + tid]);
  }

  // positional encoding -> actA
  if (tid < MT){
    int row = tid;
    int g = -1;
    if (row < cnt){
      int r = tile * MT + row;
      int sb = 0, off = 0;
      #pragma unroll
      for (int s = 0; s < 8; s++)
        if (r >= pre[s]){ sb = s; off = r - pre[s]; }
      g = bucket[chart * SEG + sb * PSEG + off];
    }
    ridx[row] = g;
    unsigned short* rowp = &actA[row * LSTR];
    if (g >= 0){
      float xv0 = x[g*3+0], xv1 = x[g*3+1], xv2 = x[g*3+2];
      rowp[0] = f2bf(xv0); rowp[1] = f2bf(xv1); rowp[2] = f2bf(xv2);
      #pragma unroll
      for (int d = 1; d <= 4; d++){
        float s = (float)(1 << d) * 3.14159265358979323846f;
        int o = 3 + (d - 1) * 6;
        rowp[o+0] = f2bf(sinf(s*xv0)); rowp[o+1] = f2bf(sinf(s*xv1)); rowp[o+2] = f2bf(sinf(s*xv2));
        rowp[o+3] = f2bf(cosf(s*xv0)); rowp[o+4] = f2bf(cosf(s*xv1)); rowp[o+5] = f2bf(cosf(s*xv2));
      }
      rowp[27] = f2bf(proc[0]); rowp[28] = f2bf(proc[1]);
      rowp[29] = 0; rowp[30] = 0; rowp[31] = 0;
    } else {
      #pragma unroll
      for (int k = 0; k < 32; k++) rowp[k] = 0;
    }
  }
  __syncthreads();

  f32x4 acc[4][2];
  const f32x4 zz = {0.f, 0.f, 0.f, 0.f};

  // Layer 0: (64x32)@(32x256); wave covers its 32 cols
  {
    const unsigned short* W0p = Wt0 + chart * 8192;
    bf16x8 b0r[2];
    #pragma unroll
    for (int nt = 0; nt < 2; nt++)
      b0r[nt] = *(const bf16x8*)&W0p[(size_t)(quad * 256 + cb + nt * 16 + l15) * 8];
    #pragma unroll
    for (int mt = 0; mt < 4; mt++){
      bf16x8 a0 = *(const bf16x8*)&actA[(mt * 16 + l15) * LSTR + quad * 8];
      #pragma unroll
      for (int nt = 0; nt < 2; nt++)
        acc[mt][nt] = __builtin_amdgcn_mfma_f32_16x16x32_bf16(a0, b0r[nt], zz, 0, 0, 0);
    }
    #pragma unroll
    for (int nt = 0; nt < 2; nt++){
      int col = cb + nt * 16 + l15;
      float bias = bf2f(biasb[col]);
      #pragma unroll
      for (int mt = 0; mt < 4; mt++)
        #pragma unroll
        for (int r = 0; r < 4; r++){
          float v = acc[mt][nt][r] + bias;
          v = v > 0.f ? v : 0.f;
          actB[(mt * 16 + quad * 4 + r) * LSTR + col] = f2bf(v);
        }
    }
  }
  __syncthreads();

  // 6 hidden layers: full 16-load slab issued up-front, static vmcnt waits
  for (int l = 1; l <= 6; l++){
    const unsigned short* wlane = Wth + ((size_t)(chart * 6 + l - 1) << 16)
                                + (size_t)(quad * 256 + cb + l15) * 8;
    const unsigned short* ain = (l & 1) ? actB : actA;
    unsigned short* aout      = (l & 1) ? actA : actB;

    bf16x8 br[8][2];
    LOADG(0); LOADG(1); LOADG(2); LOADG(3);
    LOADG(4); LOADG(5); LOADG(6); LOADG(7);   // 16 in flight

    WAITG(0, 14); MFMAG(0);
    WAITG(1, 12); MFMAG(1);
    WAITG(2, 10); MFMAG(2);
    WAITG(3, 8);  MFMAG(3);
    WAITG(4, 6);  MFMAG(4);
    WAITG(5, 4);  MFMAG(5);
    WAITG(6, 2);  MFMAG(6);
    WAITG(7, 0);  MFMAG(7);

    #pragma unroll
    for (int nt = 0; nt < 2; nt++){
      int col = cb + nt * 16 + l15;
      float bias = bf2f(biasb[l * 256 + col]);
      #pragma unroll
      for (int mt = 0; mt < 4; mt++)
        #pragma unroll
        for (int r = 0; r < 4; r++){
          float v = acc[mt][nt][r] + bias;
          v = v > 0.f ? v : 0.f;
          aout[(mt * 16 + quad * 4 + r) * LSTR + col] = f2bf(v);
        }
    }
    __syncthreads();
  }

  // Final layer: (64x256)@(256x2) + sigmoid; layer-6 output in actB
  {
    int m = tid >> 3;          // 0..63 rows
    int p = tid & 7;           // 8 threads/row, 32 k each
    const unsigned short* hrow = actB + m * LSTR + p * 32;
    const unsigned short* wlp = wlb + p * 64;
    float s0 = 0.f, s1 = 0.f;
    #pragma unroll 8
    for (int k = 0; k < 32; k += 2){
      unsigned int w01 = *(const unsigned int*)&wlp[k * 2];
      unsigned int w23 = *(const unsigned int*)&wlp[k * 2 + 2];
      unsigned int h2  = *(const unsigned int*)&hrow[k];
      float hv0 = bf2f((unsigned short)(h2 & 0xffff));
      float hv1 = bf2f((unsigned short)(h2 >> 16));
      s0 += hv0 * bf2f((unsigned short)(w01 & 0xffff)) + hv1 * bf2f((unsigned short)(w23 & 0xffff));
      s1 += hv0 * bf2f((unsigned short)(w01 >> 16))    + hv1 * bf2f((unsigned short)(w23 >> 16));
    }
    s0 += __shfl_xor(s0, 1); s0 += __shfl_xor(s0, 2); s0 += __shfl_xor(s0, 4);
    s1 += __shfl_xor(s1, 1); s1 += __shfl_xor(s1, 2); s1 += __shfl_xor(s1, 4);
    if (p == 0){
      int g = ridx[m];
      if (g >= 0){
        float o0 = 1.f / (1.f + __expf(-(s0 + bl[chart*2+0])));
        float o1 = 1.f / (1.f + __expf(-(s1 + bl[chart*2+1])));
        *(float2*)&out[(size_t)g * 2] = make_float2(o0, o1);
      }
    }
  }
}

// ---- launch ---------------------------------------------------------------

extern "C" void kernel_launch(void* const* d_in, const int* in_sizes, int n_in,
                              void* d_out, int out_size, void* d_ws, size_t ws_size,
                              hipStream_t stream){
  const float* x    = (const float*)d_in[0];
  const float* proc = (const float*)d_in[1];
  const float* W0   = (const float*)d_in[2];
  const float* b0   = (const float*)d_in[3];
  const float* Wh   = (const float*)d_in[4];
  const float* bh   = (const float*)d_in[5];
  const float* Wl   = (const float*)d_in[6];
  const float* bl   = (const float*)d_in[7];
  const int* midx = (const int*)d_in[8];
  float* out = (float*)d_out;

  char* ws = (char*)d_ws;
  int* segcnt = (int*)ws;                           // 8 segs x 8 charts
  int* bucket = segcnt + 64;                        // NCH * SEG ints
  size_t off = (((size_t)(64 + NCH * SEG)) * 4 + 15) & ~(size_t)15;
  unsigned short* Wt0 = (unsigned short*)(ws + off);  // 8 * 8192 bf16
  unsigned short* Wth = Wt0 + NCH * 8192;             // 8 * 6 * 65536 bf16

  hipLaunchKernelGGL(prep_k, dim3(208),  dim3(256), 0, stream,
                     Wh, W0, midx, Wth, Wt0, segcnt, bucket);
  hipLaunchKernelGGL(mlp_k,  dim3(2048), dim3(512), 0, stream,
                     x, proc, b0, bh, Wl, bl, Wt0, Wth, segcnt, bucket, out);
}

// Round 18
// 118.879 us; speedup vs baseline: 1.1080x; 1.0108x over previous
//
#include <hip/hip_runtime.h>
#include <hip/hip_bf16.h>
#include <math.h>

#define NPTS   16384
#define NCH    8
#define MT     32    // rows per block (2 blocks/CU co-residency)
#define LSTR   264   // act row stride (ushort)
#define SEG    16384 // fixed bucket segment per chart
#define PSEG   2048  // points per scatter sub-segment

typedef short bf16x8 __attribute__((ext_vector_type(8)));
typedef float f32x4  __attribute__((ext_vector_type(4)));

__device__ __forceinline__ float bf2f(unsigned short u){
  union { unsigned int i; float f; } v; v.i = ((unsigned int)u) << 16; return v.f;
}
__device__ __forceinline__ unsigned short f2bf(float f){
  union { float f; unsigned int i; } v; v.f = f;
  unsigned int x = v.i;
  return (unsigned short)((x + 0x7fffu + ((x >> 16) & 1u)) >> 16); // RNE
}

// ---- prep: transpose to k8-major + atomic-free bucketing (unchanged) ------

__global__ __launch_bounds__(256) void prep_k(
    const float* __restrict__ Wh, const float* __restrict__ W0,
    const int* __restrict__ midx,
    unsigned short* __restrict__ Wth, unsigned short* __restrict__ Wt0,
    int* __restrict__ segcnt, int* __restrict__ bucket){
  int bid = blockIdx.x, tid = threadIdx.x;
  if (bid < 192){
    __shared__ __align__(16) unsigned short tile[64 * LSTR];
    int mat = bid >> 2, ck = bid & 3;
    const float* src = Wh + (size_t)mat * 65536 + (size_t)ck * 64 * 256;
    int r = tid >> 2, seg = (tid & 3) * 64;
    const float* sp = &src[r * 256 + seg];
    #pragma unroll
    for (int j8 = 0; j8 < 8; j8++){
      float4 f0 = *(const float4*)&sp[j8 * 8];
      float4 f1 = *(const float4*)&sp[j8 * 8 + 4];
      __align__(16) unsigned short t8[8];
      t8[0]=f2bf(f0.x); t8[1]=f2bf(f0.y); t8[2]=f2bf(f0.z); t8[3]=f2bf(f0.w);
      t8[4]=f2bf(f1.x); t8[5]=f2bf(f1.y); t8[6]=f2bf(f1.z); t8[7]=f2bf(f1.w);
      *(uint4*)&tile[r * LSTR + seg + j8 * 8] = *(const uint4*)t8;
    }
    __syncthreads();
    unsigned short* dst = Wth + (size_t)mat * 65536 + (size_t)ck * 16384;
    #pragma unroll
    for (int it = 0; it < 8; it++){
      int s = it * 256 + tid;
      int k8l = s >> 8, n = s & 255;
      __align__(16) unsigned short t8[8];
      #pragma unroll
      for (int j = 0; j < 8; j++) t8[j] = tile[(k8l * 8 + j) * LSTR + n];
      *(uint4*)&dst[(size_t)s * 8] = *(const uint4*)t8;
    }
  } else if (bid < 200){
    int c = bid - 192;
    #pragma unroll
    for (int it = 0; it < 4; it++){
      int s = it * 256 + tid;
      int k8 = s >> 8, n = s & 255;
      __align__(16) unsigned short t8[8];
      #pragma unroll
      for (int j = 0; j < 8; j++){
        int k = k8 * 8 + j;
        t8[j] = (k < 29) ? f2bf(W0[(c * 29 + k) * 256 + n]) : (unsigned short)0;
      }
      *(uint4*)&Wt0[(size_t)c * 8192 + (size_t)s * 8] = *(const uint4*)t8;
    }
  } else {
    __shared__ int cur[NCH];
    int sb = bid - 200;
    int lane = tid & 63;
    if (tid < NCH) cur[tid] = 0;
    __syncthreads();
    for (int it = 0; it < 8; it++){
      int i = sb * PSEG + it * 256 + tid;
      int c = midx[i];
      #pragma unroll
      for (int cc = 0; cc < NCH; cc++){
        unsigned long long m = __ballot(c == cc);
        if (!m) continue;
        int leader = (int)(__ffsll((long long)m) - 1);
        int wb = 0;
        if (lane == leader) wb = atomicAdd(&cur[cc], (int)__popcll(m));
        wb = __shfl(wb, leader);
        if (c == cc){
          int rk = (int)__popcll(m & ((1ull << lane) - 1));
          bucket[cc * SEG + sb * PSEG + wb + rk] = i;
        }
      }
    }
    __syncthreads();
    if (tid < NCH) segcnt[sb * NCH + tid] = cur[tid];
  }
}

// ---- main fused MLP: MT=32, 2 blocks/CU, 4-deep asm ring, vmcnt waits -----
// EARLY-CLOBBER (=&v): outputs must not overlap the address pair (r14 crash).
// __launch_bounds__(256,2): 256-VGPR budget -> ring stays spill-free (r15 fix).

#define LOADG(slot, g) do {                                                    \
    const unsigned short* _p = wlane + (size_t)(g) * 8192;                     \
    asm volatile("global_load_dwordx4 %0, %4, off\n\t"                         \
                 "global_load_dwordx4 %1, %4, off offset:256\n\t"              \
                 "global_load_dwordx4 %2, %4, off offset:512\n\t"              \
                 "global_load_dwordx4 %3, %4, off offset:768"                  \
        : "=&v"(br[slot][0]), "=&v"(br[slot][1]),                              \
          "=&v"(br[slot][2]), "=&v"(br[slot][3])                               \
        : "v"(_p));                                                            \
  } while (0)

#define WAITG(slot, n)                                                         \
  asm volatile("s_waitcnt vmcnt(" #n ")"                                       \
      : "+v"(br[slot][0]), "+v"(br[slot][1]),                                  \
        "+v"(br[slot][2]), "+v"(br[slot][3]))

#define MFMAG(slot, g)                                                         \
  {                                                                            \
    _Pragma("unroll")                                                          \
    for (int mt = 0; mt < 2; mt++){                                            \
      bf16x8 a = *(const bf16x8*)&ain[(mt * 16 + l15) * LSTR + (g) * 32 + quad * 8]; \
      _Pragma("unroll")                                                        \
      for (int nt = 0; nt < 4; nt++)                                           \
        acc[mt][nt] = __builtin_amdgcn_mfma_f32_16x16x32_bf16(                 \
            a, br[slot][nt], ((g) == 0) ? zz : acc[mt][nt], 0, 0, 0);          \
    }                                                                          \
  }

__global__ __launch_bounds__(256, 2) void mlp_k(
    const float* __restrict__ x,
    const float* __restrict__ proc,
    const float* __restrict__ b0,
    const float* __restrict__ bh,
    const float* __restrict__ Wl,
    const float* __restrict__ bl,
    const unsigned short* __restrict__ Wt0,
    const unsigned short* __restrict__ Wth,
    const int* __restrict__ segcnt,
    const int* __restrict__ bucket,
    float* __restrict__ out)
{
  __shared__ __align__(16) unsigned short actA[MT * LSTR];
  __shared__ __align__(16) unsigned short actB[MT * LSTR];
  __shared__ unsigned short biasb[7 * 256];   // bf16
  __shared__ unsigned short wlb[512];         // bf16
  __shared__ int ridx[MT];

  int chart = blockIdx.x & 7;     // XCD swizzle
  int tile  = blockIdx.x >> 3;

  int pre[9];
  pre[0] = 0;
  #pragma unroll
  for (int s = 0; s < 8; s++) pre[s + 1] = pre[s] + segcnt[s * NCH + chart];
  int total = pre[8];
  int cnt = total - tile * MT;
  if (cnt <= 0) return;
  if (cnt > MT) cnt = MT;

  int tid  = threadIdx.x;
  int lane = tid & 63;
  int wv   = tid >> 6;
  int l15  = lane & 15;
  int quad = lane >> 4;
  int cb   = wv * 64;             // wave's output-column base (N-split)

  // stage biases + Wl (bf16)
  biasb[tid] = f2bf(b0[chart * 256 + tid]);
  #pragma unroll
  for (int j = 0; j < 6; j++)
    biasb[(j + 1) * 256 + tid] = f2bf(bh[(chart * 6 + j) * 256 + tid]);
  wlb[tid]       = f2bf(Wl[chart * 512 + tid]);
  wlb[256 + tid] = f2bf(Wl[chart * 512 + 256 + tid]);

  // positional encoding -> actA
  if (tid < MT){
    int row = tid;
    int g = -1;
    if (row < cnt){
      int r = tile * MT + row;
      int sb = 0, off = 0;
      #pragma unroll
      for (int s = 0; s < 8; s++)
        if (r >= pre[s]){ sb = s; off = r - pre[s]; }
      g = bucket[chart * SEG + sb * PSEG + off];
    }
    ridx[row] = g;
    unsigned short* rowp = &actA[row * LSTR];
    if (g >= 0){
      float xv0 = x[g*3+0], xv1 = x[g*3+1], xv2 = x[g*3+2];
      rowp[0] = f2bf(xv0); rowp[1] = f2bf(xv1); rowp[2] = f2bf(xv2);
      #pragma unroll
      for (int d = 1; d <= 4; d++){
        float s = (float)(1 << d) * 3.14159265358979323846f;
        int o = 3 + (d - 1) * 6;
        rowp[o+0] = f2bf(sinf(s*xv0)); rowp[o+1] = f2bf(sinf(s*xv1)); rowp[o+2] = f2bf(sinf(s*xv2));
        rowp[o+3] = f2bf(cosf(s*xv0)); rowp[o+4] = f2bf(cosf(s*xv1)); rowp[o+5] = f2bf(cosf(s*xv2));
      }
      rowp[27] = f2bf(proc[0]); rowp[28] = f2bf(proc[1]);
      rowp[29] = 0; rowp[30] = 0; rowp[31] = 0;
    } else {
      #pragma unroll
      for (int k = 0; k < 32; k++) rowp[k] = 0;
    }
  }
  __syncthreads();

  f32x4 acc[2][4];
  const f32x4 zz = {0.f, 0.f, 0.f, 0.f};

  // Layer 0: (32x32)@(32x256); B from Wt0 k8-major (k8 = quad)
  {
    const unsigned short* W0p = Wt0 + chart * 8192;
    bf16x8 b0r[4];
    #pragma unroll
    for (int nt = 0; nt < 4; nt++)
      b0r[nt] = *(const bf16x8*)&W0p[(size_t)(quad * 256 + cb + nt * 16 + l15) * 8];
    #pragma unroll
    for (int mt = 0; mt < 2; mt++){
      bf16x8 a0 = *(const bf16x8*)&actA[(mt * 16 + l15) * LSTR + quad * 8];
      #pragma unroll
      for (int nt = 0; nt < 4; nt++)
        acc[mt][nt] = __builtin_amdgcn_mfma_f32_16x16x32_bf16(a0, b0r[nt], zz, 0, 0, 0);
    }
    #pragma unroll
    for (int nt = 0; nt < 4; nt++){
      int col = cb + nt * 16 + l15;
      float bias = bf2f(biasb[col]);
      #pragma unroll
      for (int mt = 0; mt < 2; mt++)
        #pragma unroll
        for (int r = 0; r < 4; r++){
          float v = acc[mt][nt][r] + bias;
          v = v > 0.f ? v : 0.f;
          actB[(mt * 16 + quad * 4 + r) * LSTR + col] = f2bf(v);
        }
    }
  }
  __syncthreads();

  // 6 hidden layers: 4-deep ring of asm-issued k-groups
  for (int l = 1; l <= 6; l++){
    const unsigned short* wlane = Wth + ((size_t)(chart * 6 + l - 1) << 16)
                                + (size_t)(quad * 256 + cb + l15) * 8;
    const unsigned short* ain = (l & 1) ? actB : actA;
    unsigned short* aout      = (l & 1) ? actA : actB;

    bf16x8 br[4][4];
    LOADG(0, 0); LOADG(1, 1); LOADG(2, 2); LOADG(3, 3);   // 16 in flight

    WAITG(0, 12); MFMAG(0, 0); LOADG(0, 4);
    WAITG(1, 12); MFMAG(1, 1); LOADG(1, 5);
    WAITG(2, 12); MFMAG(2, 2); LOADG(2, 6);
    WAITG(3, 12); MFMAG(3, 3); LOADG(3, 7);
    WAITG(0, 12); MFMAG(0, 4);
    WAITG(1, 8);  MFMAG(1, 5);
    WAITG(2, 4);  MFMAG(2, 6);
    WAITG(3, 0);  MFMAG(3, 7);

    #pragma unroll
    for (int nt = 0; nt < 4; nt++){
      int col = cb + nt * 16 + l15;
      float bias = bf2f(biasb[l * 256 + col]);
      #pragma unroll
      for (int mt = 0; mt < 2; mt++)
        #pragma unroll
        for (int r = 0; r < 4; r++){
          float v = acc[mt][nt][r] + bias;
          v = v > 0.f ? v : 0.f;
          aout[(mt * 16 + quad * 4 + r) * LSTR + col] = f2bf(v);
        }
    }
    __syncthreads();
  }

  // Final layer: (32x256)@(256x2) + sigmoid; layer-6 output in actB
  {
    int m = tid >> 3;          // 0..31 rows
    int p = tid & 7;           // 8 threads/row, 32 k each
    const unsigned short* hrow = actB + m * LSTR + p * 32;
    const unsigned short* wlp = wlb + p * 64;
    float s0 = 0.f, s1 = 0.f;
    #pragma unroll 8
    for (int k = 0; k < 32; k += 2){
      unsigned int w01 = *(const unsigned int*)&wlp[k * 2];
      unsigned int w23 = *(const unsigned int*)&wlp[k * 2 + 2];
      unsigned int h2  = *(const unsigned int*)&hrow[k];
      float hv0 = bf2f((unsigned short)(h2 & 0xffff));
      float hv1 = bf2f((unsigned short)(h2 >> 16));
      s0 += hv0 * bf2f((unsigned short)(w01 & 0xffff)) + hv1 * bf2f((unsigned short)(w23 & 0xffff));
      s1 += hv0 * bf2f((unsigned short)(w01 >> 16))    + hv1 * bf2f((unsigned short)(w23 >> 16));
    }
    s0 += __shfl_xor(s0, 1); s0 += __shfl_xor(s0, 2); s0 += __shfl_xor(s0, 4);
    s1 += __shfl_xor(s1, 1); s1 += __shfl_xor(s1, 2); s1 += __shfl_xor(s1, 4);
    if (p == 0){
      int g = ridx[m];
      if (g >= 0){
        float o0 = 1.f / (1.f + __expf(-(s0 + bl[chart*2+0])));
        float o1 = 1.f / (1.f + __expf(-(s1 + bl[chart*2+1])));
        *(float2*)&out[(size_t)g * 2] = make_float2(o0, o1);
      }
    }
  }
}

// ---- launch ---------------------------------------------------------------

extern "C" void kernel_launch(void* const* d_in, const int* in_sizes, int n_in,
                              void* d_out, int out_size, void* d_ws, size_t ws_size,
                              hipStream_t stream){
  const float* x    = (const float*)d_in[0];
  const float* proc = (const float*)d_in[1];
  const float* W0   = (const float*)d_in[2];
  const float* b0   = (const float*)d_in[3];
  const float* Wh   = (const float*)d_in[4];
  const float* bh   = (const float*)d_in[5];
  const float* Wl   = (const float*)d_in[6];
  const float* bl   = (const float*)d_in[7];
  const int* midx = (const int*)d_in[8];
  float* out = (float*)d_out;

  char* ws = (char*)d_ws;
  int* segcnt = (int*)ws;                           // 8 segs x 8 charts
  int* bucket = segcnt + 64;                        // NCH * SEG ints
  size_t off = (((size_t)(64 + NCH * SEG)) * 4 + 15) & ~(size_t)15;
  unsigned short* Wt0 = (unsigned short*)(ws + off);  // 8 * 8192 bf16
  unsigned short* Wth = Wt0 + NCH * 8192;             // 8 * 6 * 65536 bf16

  hipLaunchKernelGGL(prep_k, dim3(208),  dim3(256), 0, stream,
                     Wh, W0, midx, Wth, Wt0, segcnt, bucket);
  hipLaunchKernelGGL(mlp_k,  dim3(4096), dim3(256), 0, stream,
                     x, proc, b0, bh, Wl, bl, Wt0, Wth, segcnt, bucket, out);
}